// Round 1
// baseline (107.578 us; speedup 1.0000x reference)
//
#include <hip/hip_runtime.h>
#include <math.h>

#define B_   16
#define N_   32
#define I_   1152
#define DIN  16
#define D_   64
#define IB   72            // i-tiles of 16 in k_xhat
#define BND  (B_*N_*D_)    // 32768

#if __has_builtin(__builtin_amdgcn_exp2f)
#define EXP2(x) __builtin_amdgcn_exp2f(x)
#else
#define EXP2(x) exp2f(x)
#endif

#define LOG2E 1.4426950408889634f

__device__ __forceinline__ float squash1(float s) {
    float sq = s * s;
    return (sq / (1.0f + sq)) * s * rsqrtf(sq + 1e-9f);
}

// K1: x_hat[b][n][i][d] = dot16(W[n,i,d,:], inputs[b,i,:]); also per-block
// partial sums over the 16-i tile for s0 (deterministic, no atomics).
// grid = N_*IB blocks, 256 threads. partials layout: part[ib][b][n][d].
__global__ __launch_bounds__(256) void k_xhat(const float* __restrict__ inp,
                                              const float* __restrict__ W,
                                              float* __restrict__ xh,
                                              float* __restrict__ part) {
    __shared__ __align__(16) float lds[4096];   // stage: [b][il][k] ; then reduce: [g][b][d]
    const int bx = blockIdx.x;
    const int n  = bx / IB;
    const int ib = bx % IB;
    const int i0 = ib * 16;
    const int t  = threadIdx.x;

    // stage inputs[b][i0:i0+16][0:16] -> lds[b*256 + il*16 + k]  (16 KB)
    {
        float4* l4 = (float4*)lds;
        #pragma unroll
        for (int j = 0; j < 4; ++j) {
            int id = t + j * 256;          // 0..1023 float4s
            int b  = id >> 6;
            int r  = id & 63;
            const float4* s4 = (const float4*)(inp + (size_t)b * (I_ * DIN) + (size_t)i0 * DIN);
            l4[b * 64 + r] = s4[r];
        }
    }
    __syncthreads();

    const int d = t & 63;
    const int g = t >> 6;                  // 4 groups, each handles 4 i's

    float s0[B_];
    #pragma unroll
    for (int b = 0; b < B_; ++b) s0[b] = 0.0f;

    #pragma unroll
    for (int ii = 0; ii < 4; ++ii) {
        const int il = g * 4 + ii;
        const int i  = i0 + il;
        const float4* wp = (const float4*)(W + ((size_t)(n * I_ + i) * D_ + d) * DIN);
        float4 w0 = wp[0], w1 = wp[1], w2 = wp[2], w3 = wp[3];
        #pragma unroll
        for (int b = 0; b < B_; ++b) {
            const float4* q4 = (const float4*)(lds + b * 256 + il * 16);
            float4 a0 = q4[0], a1 = q4[1], a2 = q4[2], a3 = q4[3];
            float v = w0.x*a0.x + w0.y*a0.y + w0.z*a0.z + w0.w*a0.w
                    + w1.x*a1.x + w1.y*a1.y + w1.z*a1.z + w1.w*a1.w
                    + w2.x*a2.x + w2.y*a2.y + w2.z*a2.z + w2.w*a2.w
                    + w3.x*a3.x + w3.y*a3.y + w3.z*a3.z + w3.w*a3.w;
            xh[((size_t)(b * N_ + n) * I_ + i) * D_ + d] = v;
            s0[b] += v;
        }
    }

    __syncthreads();
    // write per-thread partials into lds[g][b][d], then wave 0 reduces over g
    #pragma unroll
    for (int b = 0; b < B_; ++b) lds[g * 1024 + b * 64 + d] = s0[b];
    __syncthreads();
    if (t < 64) {
        #pragma unroll
        for (int b = 0; b < B_; ++b) {
            float s = lds[b * 64 + t] + lds[1024 + b * 64 + t]
                    + lds[2048 + b * 64 + t] + lds[3072 + b * 64 + t];
            part[(size_t)ib * BND + (size_t)(b * N_ + n) * D_ + t] = s;
        }
    }
}

// K2: coef = squash(mean over i of x_hat) — iteration 0 (softmax of zeros is uniform)
__global__ __launch_bounds__(256) void k_out0(const float* __restrict__ part,
                                              float* __restrict__ coef) {
    const int t = blockIdx.x * 256 + threadIdx.x;   // 0..BND-1
    float s = 0.0f;
    for (int j = 0; j < IB; ++j) s += part[(size_t)j * BND + t];
    s *= (1.0f / (float)I_);
    coef[t] = squash1(s);
}

// K3/K4: one routing iteration. logits l_i = x_hat[b,n,i,d] * coef[b,n,d].
// Online softmax over i (exp2 domain, LOG2E folded into coef), s = sum c*x.
// final=0: coef += squash(s). final=1: out = squash(s).
// grid = B_*N_ blocks, 512 threads (8 i-stripes of 144, lane = d).
__global__ __launch_bounds__(512) void k_route(const float* __restrict__ xh,
                                               const float* __restrict__ coef_in,
                                               float* __restrict__ outp,
                                               int final_) {
    const int bx = blockIdx.x;             // b*N_ + n
    const int t  = threadIdx.x;
    const int d  = t & 63;
    const int g  = t >> 6;
    const float* base = xh + (size_t)bx * (I_ * D_);
    const float c  = coef_in[bx * D_ + d];
    const float c2 = c * LOG2E;

    float m = -INFINITY, Z = 0.0f, A = 0.0f;
    const int i0 = g * (I_ / 8);           // 144 per stripe
    #pragma unroll 4
    for (int j = 0; j < I_ / 8; ++j) {
        float x  = base[(size_t)(i0 + j) * D_ + d];
        float l  = x * c2;
        float nm = fmaxf(m, l);
        float e1 = EXP2(m - nm);
        float e2 = EXP2(l - nm);
        Z = Z * e1 + e2;
        A = A * e1 + e2 * x;
        m = nm;
    }

    __shared__ float ms[512], zs[512], as_[512];
    ms[t] = m; zs[t] = Z; as_[t] = A;
    __syncthreads();
    if (t < 64) {
        float M = -INFINITY;
        #pragma unroll
        for (int gg = 0; gg < 8; ++gg) M = fmaxf(M, ms[gg * 64 + t]);
        float Zt = 0.0f, At = 0.0f;
        #pragma unroll
        for (int gg = 0; gg < 8; ++gg) {
            float e = EXP2(ms[gg * 64 + t] - M);
            Zt += zs[gg * 64 + t] * e;
            At += as_[gg * 64 + t] * e;
        }
        float s = At / Zt;
        float o = squash1(s);
        if (final_) outp[bx * D_ + t] = o;
        else        outp[bx * D_ + t] = c + o;
    }
}

extern "C" void kernel_launch(void* const* d_in, const int* in_sizes, int n_in,
                              void* d_out, int out_size, void* d_ws, size_t ws_size,
                              hipStream_t stream) {
    const float* inp = (const float*)d_in[0];
    const float* W   = (const float*)d_in[1];
    float* out  = (float*)d_out;

    float* xh   = (float*)d_ws;                       // 37,748,736 floats (151 MB)
    float* part = xh + (size_t)B_ * N_ * I_ * D_;     // 72*32768 floats (9.4 MB)
    float* coef = part + (size_t)IB * BND;            // 32768 floats

    k_xhat <<<dim3(N_ * IB), dim3(256), 0, stream>>>(inp, W, xh, part);
    k_out0 <<<dim3(BND / 256), dim3(256), 0, stream>>>(part, coef);
    k_route<<<dim3(B_ * N_), dim3(512), 0, stream>>>(xh, coef, coef, 0);
    k_route<<<dim3(B_ * N_), dim3(512), 0, stream>>>(xh, coef, out, 1);
}